// Round 5
// baseline (1529.535 us; speedup 1.0000x reference)
//
#include <hip/hip_runtime.h>

// s_gcn fused: out[n,c,t,w] = sum_k sum_v (W[k*64+c,:]·x[n,:,t,v] + b[k*64+c]) * A[k,v,w]
// x (16,64,2048,25) f32, A (3,25,25), W (192,64), b (192,), out (16,64,2048,25)
//
// R5 structure: LDS-pipe was the wall (~615us of ds_read_b128 in R4).
//  - x rows are wave-uniform (lane=c, one t per wave) -> uniform/SMEM global
//    loads via readfirstlane base, NOT LDS. xs tile + staging deleted.
//  - A rows uniform -> global scalar loads in epilogue (7.5KB, sL1-resident),
//    used as SGPR operands in v_fma. as[] deleted.
//  - Only W in LDS (per-lane c), staged ONCE per block, no hot-loop barriers.
//  - Block = (n, all c, 32 t): per-(n,c) output run = 3200 B = 25 full lines,
//    128B-aligned, no cross-block line sharing -> direct stores, clean writes.

#define K_NUM   3
#define C_IN    64
#define C_OUT   64
#define T_DIM   2048
#define V_DIM   25
#define N_DIM   16
#define T_LOCAL 32   // t-window per block
#define T_BLK   4    // t per iteration (one per wave)

typedef float ufloat4 __attribute__((ext_vector_type(4), aligned(4)));
typedef float nfloat2 __attribute__((ext_vector_type(2)));

__global__ __launch_bounds__(256, 3)
void sgcn_fused(const float* __restrict__ x,
                const float* __restrict__ A,
                const float* __restrict__ W,
                const float* __restrict__ b,
                float* __restrict__ out) {
    __shared__ nfloat2 wsd[C_IN * C_OUT];   // {W[c][ci], W[64+c][ci]}  32 KB
    __shared__ float   wse[C_IN * C_OUT];   //  W[128+c][ci]            16 KB

    const int tid = threadIdx.x;
    const int bid = blockIdx.x;
    const int nb  = bid >> 6;            // n
    const int t0  = (bid & 63) * T_LOCAL;
    const int c   = tid & 63;            // lane = output channel
    const int tl  = tid >> 6;            // wave = t-slot

    // ---- stage W once: wsd/wse[ci*64 + c] ----
    for (int i = tid; i < C_IN * C_OUT; i += 256) {
        const int ci = i >> 6, cc = i & 63;
        wsd[i] = nfloat2{W[(0 * C_OUT + cc) * C_IN + ci],
                         W[(1 * C_OUT + cc) * C_IN + ci]};
        wse[i] = W[(2 * C_OUT + cc) * C_IN + ci];
    }
    __syncthreads();   // only barrier in the kernel

    const float b0 = b[c], b1 = b[C_OUT + c], b2 = b[2 * C_OUT + c];

    #pragma unroll 1
    for (int it = 0; it < T_LOCAL / T_BLK; ++it) {
        const int t = t0 + it * T_BLK + tl;

        float h0[V_DIM], h1[V_DIM], h2[V_DIM];
        #pragma unroll
        for (int v = 0; v < V_DIM; ++v) { h0[v] = b0; h1[v] = b1; h2[v] = b2; }

        // wave-uniform row base (forces SGPR address -> scalar/broadcast loads)
        const int rowbase =
            __builtin_amdgcn_readfirstlane((nb * C_IN * T_DIM + t) * V_DIM);

        #pragma unroll 2
        for (int ci = 0; ci < C_IN; ++ci) {
            const nfloat2 wd = wsd[ci * C_OUT + c];   // 8B-stride lanes, conflict-free
            const float   we = wse[ci * C_OUT + c];   // 4B-stride, 2-way = free
            const float* xr = x + rowbase + ci * (T_DIM * V_DIM);  // uniform
            float xv[V_DIM];
            #pragma unroll
            for (int v = 0; v < V_DIM; ++v) xv[v] = xr[v];
            #pragma unroll
            for (int v = 0; v < V_DIM; ++v) {
                h0[v] = fmaf(wd.x, xv[v], h0[v]);
                h1[v] = fmaf(wd.y, xv[v], h1[v]);
                h2[v] = fmaf(we,   xv[v], h2[v]);
            }
        }

        // ---- epilogue: acc[w] = sum_k sum_v h[k][v]*A[k][v][w]; A uniform ----
        float acc[V_DIM];
        #pragma unroll
        for (int w = 0; w < V_DIM; ++w) acc[w] = 0.f;

        #pragma unroll
        for (int v = 0; v < V_DIM; ++v) {
            const float* Ar0 = A + v * V_DIM;                     // k=0 row
            const float* Ar1 = A + (V_DIM * V_DIM) + v * V_DIM;   // k=1
            const float* Ar2 = A + 2 * (V_DIM * V_DIM) + v * V_DIM;
            const float hv0 = h0[v], hv1 = h1[v], hv2 = h2[v];
            #pragma unroll
            for (int w = 0; w < V_DIM; ++w)
                acc[w] = fmaf(hv0, Ar0[w],
                         fmaf(hv1, Ar1[w],
                         fmaf(hv2, Ar2[w], acc[w])));
        }

        // ---- direct store: 25 floats, lines owned exclusively by this block ----
        float* op = out + ((size_t)(nb * C_OUT + c) * T_DIM + t) * V_DIM;
        #pragma unroll
        for (int q = 0; q < 6; ++q) {
            ufloat4 s = {acc[4*q], acc[4*q+1], acc[4*q+2], acc[4*q+3]};
            *reinterpret_cast<ufloat4*>(op + 4 * q) = s;
        }
        op[24] = acc[24];
    }
}

extern "C" void kernel_launch(void* const* d_in, const int* in_sizes, int n_in,
                              void* d_out, int out_size, void* d_ws, size_t ws_size,
                              hipStream_t stream) {
    const float* x = (const float*)d_in[0];
    const float* A = (const float*)d_in[1];
    const float* W = (const float*)d_in[2];
    const float* b = (const float*)d_in[3];
    float* out = (float*)d_out;

    dim3 grid(N_DIM * (T_DIM / T_LOCAL));   // 16 * 64 = 1024 blocks
    sgcn_fused<<<grid, 256, 0, stream>>>(x, A, W, b, out);
}

// Round 6
// 280.871 us; speedup vs baseline: 5.4457x; 5.4457x over previous
//
#include <hip/hip_runtime.h>

// s_gcn via bf16-split MFMA, two fused GEMM stages.
//   stage-1: H[o=192][cols] = Wcat[192x128] * Xcat[128xcols]   (K=128 = ci x {hi,lo})
//   stage-2: OUT[c][w]     += H_k[c][64] * At_k[64x32]         (K=64  = v x {hi,lo}, k=0..2)
// W/A fragment buffers pre-packed into d_ws by a prep kernel (read from global,
// off the LDS pipe). x staged to LDS transposed with v padded 25->32; H staged
// as packed (hi,lo) bf16 pairs. XOR swizzle ((r&7)^((r>>2)&7))<<4 on all LDS rows.

typedef short short8 __attribute__((ext_vector_type(8)));
typedef float floatx4 __attribute__((ext_vector_type(4)));

#define K_NUM 3
#define C_IN  64
#define C_OUT 64
#define T_DIM 2048
#define V_DIM 25
#define N_DIM 16

#define TT    2                  // t per subtile
#define NSUB  16                 // subtiles per block
#define TWIN  (TT*NSUB)          // 32 t per block window
#define COLS  (TT*32)            // 64 padded cols (v padded to 32)

#define WBUF_ELEMS (12*4*64*8)   // [mt12][ks4][lane64][j8]
#define ABUF_OFF   49152         // bytes; wbuf = 24576 u16
#define ABUF_ELEMS (3*2*2*64*8)  // [k3][nt2][ks2][lane64][j8]

__device__ __forceinline__ unsigned short bf16_rne(float f) {
    unsigned int u = __builtin_bit_cast(unsigned int, f);
    unsigned int r = (u + 0x7FFFu + ((u >> 16) & 1u)) >> 16;
    return (unsigned short)r;
}
__device__ __forceinline__ float bf16_f32(unsigned short h) {
    return __builtin_bit_cast(float, (unsigned int)h << 16);
}
__device__ __forceinline__ int swzf(int row) { return (row & 7) ^ ((row >> 2) & 7); }

// ---- prep: pack W and A into MFMA fragment order (bf16) ----
// A-operand lane map assumed: m = lane&15, k = (lane>>4)*8 + j
// B-operand lane map assumed: n = lane&15, k = (lane>>4)*8 + j
__global__ void sgcn_prep(const float* __restrict__ W, const float* __restrict__ A,
                          unsigned short* __restrict__ wbuf, unsigned short* __restrict__ abuf) {
    int idx = blockIdx.x * 256 + threadIdx.x;
    if (idx < WBUF_ELEMS) {
        int j = idx & 7, lane = (idx >> 3) & 63, ks = (idx >> 9) & 3, mt = idx >> 11;
        int o  = mt * 16 + (lane & 15);
        int kk = ks * 32 + (lane >> 4) * 8 + j;   // 0..127
        int ci = kk >> 1;                         // hi/lo interleaved -> same W both
        wbuf[idx] = bf16_rne(W[o * C_IN + ci]);
    }
    if (idx < ABUF_ELEMS) {
        int j = idx & 7, lane = (idx >> 3) & 63, ks = (idx >> 9) & 1, nt = (idx >> 10) & 1, k = idx >> 11;
        int w  = nt * 16 + (lane & 15);
        int kk = ks * 32 + (lane >> 4) * 8 + j;   // 0..63
        int v  = kk >> 1;                         // (hh,hl) pairs both hit Ah
        float val = (v < V_DIM && w < V_DIM) ? A[(k * V_DIM + v) * V_DIM + w] : 0.f;
        abuf[idx] = bf16_rne(val);
    }
}

__global__ __launch_bounds__(512)
void sgcn_main(const float* __restrict__ x, const float* __restrict__ b,
               const unsigned short* __restrict__ wbuf,
               const unsigned short* __restrict__ abuf,
               float* __restrict__ out) {
    __shared__ unsigned short Xt[COLS * 128];           // [col][kk=2ci+pl], 16 KB
    __shared__ unsigned short H2[K_NUM * TT * 64 * 64]; // [k][t][c][kk=2v+pl], 48 KB

    const int tid  = threadIdx.x;
    const int lane = tid & 63;
    const int wid  = tid >> 6;        // 0..7
    const int nb   = blockIdx.x >> 6;
    const int win  = blockIdx.x & 63;
    const int t_base = win * TWIN;

    // stage-1 wave split: 2 m-halves x 4 n-tiles
    const int wm = wid & 1, wn = wid >> 1;
    // stage-2 wave split: 4 m-tiles x 2 t
    const int mt2 = wid & 3, th = wid >> 2;

    // bias held in regs: o = (wm*6+im)*16 + (lane>>4)*4 + r
    floatx4 bias6[6];
    {
        int r0 = (lane >> 4) * 4;
        #pragma unroll
        for (int im = 0; im < 6; ++im) {
            int o0 = (wm * 6 + im) * 16 + r0;
            bias6[im] = floatx4{b[o0], b[o0 + 1], b[o0 + 2], b[o0 + 3]};
        }
    }

    // zero the never-written padded Xt cols (25..31, 57..63) once
    for (int i = tid; i < 14 * 64; i += 512) {
        int pc = i >> 6, ci = i & 63;
        int col = (pc < 7) ? (25 + pc) : (50 + pc);
        ((unsigned int*)Xt)[(col * 64 + ci) ^ (swzf(col) * 4)] = 0u;
    }

    const int bcol = wn * 16 + (lane & 15);       // stage-1 B col (per-lane)
    const int t_c  = bcol >> 5, v_c = bcol & 31;  // col -> (t, v)
    const int c_a  = mt2 * 16 + (lane & 15);      // stage-2 A-operand c row

    for (int ts = 0; ts < NSUB; ++ts) {
        __syncthreads();   // prev stage-2 H2 reads done; safe to restage

        // ---- stage x tile: 64 ci rows x 50 f32 cols, transposed + hi/lo split ----
        {
            const float2* xsrc = (const float2*)(x + ((size_t)nb * C_IN * T_DIM + t_base + ts * TT) * V_DIM);
            for (int u = tid; u < 1600; u += 512) {          // 25 f2-cols x 64 ci
                int ci = u / 25, q = u % 25;
                float2 val = xsrc[(size_t)ci * (T_DIM * V_DIM / 2) + q];
                #pragma unroll
                for (int e = 0; e < 2; ++e) {
                    int colg = 2 * q + e;
                    float f  = e ? val.y : val.x;
                    int col  = (colg >= 25) ? (colg + 7) : colg;   // t*32 + v
                    unsigned short hh = bf16_rne(f);
                    unsigned short hl = bf16_rne(f - bf16_f32(hh));
                    unsigned int packed = (unsigned int)hh | ((unsigned int)hl << 16);
                    ((unsigned int*)Xt)[(col * 64 + ci) ^ (swzf(col) * 4)] = packed;
                }
            }
        }
        __syncthreads();   // Xt ready

        // ---- stage-1: H = Wcat * Xcat, M=192 N=64 K=128 ----
        {
            short8 bfr[4];
            #pragma unroll
            for (int ks = 0; ks < 4; ++ks)
                bfr[ks] = ((short8*)Xt)[(bcol * 16 + ks * 4 + (lane >> 4)) ^ swzf(bcol)];

            floatx4 acc1[6];
            #pragma unroll
            for (int im = 0; im < 6; ++im) acc1[im] = bias6[im];

            #pragma unroll
            for (int im = 0; im < 6; ++im) {
                int mt = wm * 6 + im;
                #pragma unroll
                for (int ks = 0; ks < 4; ++ks) {
                    short8 afr = ((const short8*)wbuf)[(mt * 4 + ks) * 64 + lane];
                    acc1[im] = __builtin_amdgcn_mfma_f32_16x16x32_bf16(afr, bfr[ks], acc1[im], 0, 0, 0);
                }
            }

            // write H2: packed (hh,hl) at [k][t][c][2v]
            #pragma unroll
            for (int im = 0; im < 6; ++im) {
                int mt = wm * 6 + im;
                #pragma unroll
                for (int r = 0; r < 4; ++r) {
                    int o = mt * 16 + (lane >> 4) * 4 + r;
                    int k = o >> 6, c = o & 63;
                    float h = acc1[im][r];
                    unsigned short hh = bf16_rne(h);
                    unsigned short hl = bf16_rne(h - bf16_f32(hh));
                    unsigned int packed = (unsigned int)hh | ((unsigned int)hl << 16);
                    int row = (k * TT + t_c) * 64 + c;
                    ((unsigned int*)H2)[(row * 32 + v_c) ^ (swzf(c) * 4)] = packed;
                }
            }
        }
        __syncthreads();   // H2 ready

        // ---- stage-2: OUT[c][w] = sum_k H_k * At_k, M=64 N=32 K=64 ----
        {
            floatx4 acc2[2];
            acc2[0] = floatx4{0.f, 0.f, 0.f, 0.f};
            acc2[1] = floatx4{0.f, 0.f, 0.f, 0.f};
            #pragma unroll
            for (int k = 0; k < K_NUM; ++k) {
                short8 ha[2];
                int row = (k * TT + th) * 64 + c_a;
                #pragma unroll
                for (int ks = 0; ks < 2; ++ks)
                    ha[ks] = ((short8*)H2)[(row * 8 + ks * 4 + (lane >> 4)) ^ swzf(c_a)];
                #pragma unroll
                for (int nt = 0; nt < 2; ++nt) {
                    #pragma unroll
                    for (int ks = 0; ks < 2; ++ks) {
                        short8 ab = ((const short8*)abuf)[((k * 2 + nt) * 2 + ks) * 64 + lane];
                        acc2[nt] = __builtin_amdgcn_mfma_f32_16x16x32_bf16(ha[ks], ab, acc2[nt], 0, 0, 0);
                    }
                }
            }

            // store: c = mt2*16 + (lane>>4)*4 + r, w = nt*16 + (lane&15)
            const int tg = t_base + ts * TT + th;
            const int c0 = mt2 * 16 + (lane >> 4) * 4;
            const int wl = lane & 15;
            #pragma unroll
            for (int r = 0; r < 4; ++r)
                out[((size_t)(nb * C_OUT + c0 + r) * T_DIM + tg) * V_DIM + wl] = acc2[0][r];
            if (wl < 9) {
                #pragma unroll
                for (int r = 0; r < 4; ++r)
                    out[((size_t)(nb * C_OUT + c0 + r) * T_DIM + tg) * V_DIM + 16 + wl] = acc2[1][r];
            }
        }
    }
}

extern "C" void kernel_launch(void* const* d_in, const int* in_sizes, int n_in,
                              void* d_out, int out_size, void* d_ws, size_t ws_size,
                              hipStream_t stream) {
    const float* x = (const float*)d_in[0];
    const float* A = (const float*)d_in[1];
    const float* W = (const float*)d_in[2];
    const float* b = (const float*)d_in[3];
    float* out = (float*)d_out;

    unsigned short* wbuf = (unsigned short*)d_ws;
    unsigned short* abuf = (unsigned short*)((char*)d_ws + ABUF_OFF);

    sgcn_prep<<<(WBUF_ELEMS + 255) / 256, 256, 0, stream>>>(W, A, wbuf, abuf);

    dim3 grid(N_DIM * (T_DIM / TWIN));   // 16 * 64 = 1024 blocks
    sgcn_main<<<grid, 512, 0, stream>>>(x, b, wbuf, abuf, out);
}